// Round 2
// baseline (911.818 us; speedup 1.0000x reference)
//
#include <hip/hip_runtime.h>
#include <hip/hip_bf16.h>
#include <stdint.h>

typedef __bf16 bf16_t;
typedef __bf16 bf16x8 __attribute__((ext_vector_type(8)));
typedef float f32x4 __attribute__((ext_vector_type(4)));

#define SEQ    4096
#define NROWS  16384   // B * N
#define DMODEL 1024
#define NH     16

// ---------------- fp32 -> bf16 convert (weights only; 8 elems/thread) ----------------
__global__ __launch_bounds__(256) void f2b_kernel(const float* __restrict__ x,
                                                  bf16_t* __restrict__ y, int n8) {
  int i = blockIdx.x * 256 + threadIdx.x;
  if (i >= n8) return;
  const float4* xp = (const float4*)x + (size_t)i * 2;
  float4 a = xp[0], b = xp[1];
  bf16x8 o;
  o[0] = (bf16_t)a.x; o[1] = (bf16_t)a.y; o[2] = (bf16_t)a.z; o[3] = (bf16_t)a.w;
  o[4] = (bf16_t)b.x; o[5] = (bf16_t)b.y; o[6] = (bf16_t)b.z; o[7] = (bf16_t)b.w;
  *((bf16x8*)y + i) = o;
}

// ---------------- zero kv ----------------
__global__ __launch_bounds__(256) void zero_kernel(float* __restrict__ p, int n4) {
  int i = blockIdx.x * 256 + threadIdx.x;
  if (i < n4) ((float4*)p)[i] = make_float4(0.f, 0.f, 0.f, 0.f);
}

// ---------------- GEMM with fp32 A (in-register cvt) ----------------
// C[m,n] = sum_k A[m,k]*Bt[n,k] + bias[n]
// 128x128 tile, BK=64, 4 waves, mfma_f32_16x16x32_bf16.
// FUSE_QNORM: instead of writing C, L2-normalize each row's head-segment
// (wave strip == one head) scaled by gamma[h] and write qn[(b*NH+h)*SEQ+n][kk].
template <bool FUSE_QNORM>
__global__ __launch_bounds__(256) void gemm_a32_bt(const float* __restrict__ A,
                                                   const bf16_t* __restrict__ Bt,
                                                   const float* __restrict__ bias,
                                                   bf16_t* __restrict__ C,
                                                   bf16_t* __restrict__ qn,
                                                   const float* __restrict__ gamma,
                                                   int M, int N, int K) {
  __shared__ bf16_t sA[128 * 64];
  __shared__ bf16_t sB[128 * 64];
  const int tid  = threadIdx.x;
  const int lane = tid & 63;
  const int wave = tid >> 6;
  const int m0 = blockIdx.y * 128;
  const int n0 = blockIdx.x * 128;
  const int wm = (wave & 1) * 64;
  const int wn = (wave >> 1) * 64;
  const int lrow = lane & 15;
  const int quad = lane >> 4;

  f32x4 zero = {0.f, 0.f, 0.f, 0.f};
  f32x4 acc[4][4];
#pragma unroll
  for (int i = 0; i < 4; ++i)
#pragma unroll
    for (int j = 0; j < 4; ++j) acc[i][j] = zero;

  for (int kb = 0; kb < K; kb += 64) {
    float4 ra[4][2];
    uint4 rb[4];
#pragma unroll
    for (int i = 0; i < 4; ++i) {
      int c = i * 256 + tid;
      int row = c >> 3;
      int cc = (c & 7) * 8;
      const float* ap = A + (size_t)(m0 + row) * K + kb + cc;
      ra[i][0] = *(const float4*)ap;
      ra[i][1] = *(const float4*)(ap + 4);
      rb[i] = *(const uint4*)(Bt + (size_t)(n0 + row) * K + kb + cc);
    }
    __syncthreads();  // previous compute done before overwriting LDS
#pragma unroll
    for (int i = 0; i < 4; ++i) {
      int c = i * 256 + tid;
      bf16x8 o;
      o[0] = (bf16_t)ra[i][0].x; o[1] = (bf16_t)ra[i][0].y;
      o[2] = (bf16_t)ra[i][0].z; o[3] = (bf16_t)ra[i][0].w;
      o[4] = (bf16_t)ra[i][1].x; o[5] = (bf16_t)ra[i][1].y;
      o[6] = (bf16_t)ra[i][1].z; o[7] = (bf16_t)ra[i][1].w;
      *(bf16x8*)(sA + c * 8) = o;
      *(uint4*)(sB + c * 8) = rb[i];
    }
    __syncthreads();
#pragma unroll
    for (int ks = 0; ks < 2; ++ks) {
      bf16x8 af[4], bfr[4];
#pragma unroll
      for (int i = 0; i < 4; ++i)
        af[i] = *(const bf16x8*)(sA + (wm + i * 16 + lrow) * 64 + ks * 32 + quad * 8);
#pragma unroll
      for (int j = 0; j < 4; ++j)
        bfr[j] = *(const bf16x8*)(sB + (wn + j * 16 + lrow) * 64 + ks * 32 + quad * 8);
#pragma unroll
      for (int i = 0; i < 4; ++i)
#pragma unroll
        for (int j = 0; j < 4; ++j)
          acc[i][j] = __builtin_amdgcn_mfma_f32_16x16x32_bf16(af[i], bfr[j], acc[i][j], 0, 0, 0);
    }
  }

  float bv[4];
#pragma unroll
  for (int j = 0; j < 4; ++j) bv[j] = bias[n0 + wn + j * 16 + lrow];

  if constexpr (FUSE_QNORM) {
    const int h = (n0 + wn) >> 6;          // wave strip == one head
    const float g = gamma[h];
#pragma unroll
    for (int i = 0; i < 4; ++i) {
#pragma unroll
      for (int r = 0; r < 4; ++r) {
        float val[4];
        float ss = 0.f;
#pragma unroll
        for (int j = 0; j < 4; ++j) {
          val[j] = acc[i][j][r] + bv[j];
          ss += val[j] * val[j];
        }
        // reduce over the 16 lanes (lrow) of this quad -> full 64-col sum
        ss += __shfl_xor(ss, 1);
        ss += __shfl_xor(ss, 2);
        ss += __shfl_xor(ss, 4);
        ss += __shfl_xor(ss, 8);
        float scale = g * rsqrtf(ss);
        int row = m0 + wm + i * 16 + quad * 4 + r;
        int b_ = row >> 12, n = row & (SEQ - 1);
        bf16_t* dst = qn + ((size_t)(b_ * NH + h) * SEQ + n) * 64;
#pragma unroll
        for (int j = 0; j < 4; ++j) dst[j * 16 + lrow] = (bf16_t)(val[j] * scale);
      }
    }
  } else {
#pragma unroll
    for (int i = 0; i < 4; ++i) {
      int row = m0 + wm + i * 16 + quad * 4;
#pragma unroll
      for (int j = 0; j < 4; ++j) {
        int col = n0 + wn + j * 16 + lrow;
#pragma unroll
        for (int r = 0; r < 4; ++r)
          C[(size_t)(row + r) * N + col] = (bf16_t)(acc[i][j][r] + bv[j]);
      }
    }
  }
}

// ---------------- GEMM with bf16 A, fp32 out (final projection) ----------------
__global__ __launch_bounds__(256) void gemm_bt_f32out(const bf16_t* __restrict__ A,
                                                      const bf16_t* __restrict__ Bt,
                                                      const float* __restrict__ bias,
                                                      float* __restrict__ C,
                                                      int M, int N, int K) {
  __shared__ bf16_t sA[128 * 64];
  __shared__ bf16_t sB[128 * 64];
  const int tid  = threadIdx.x;
  const int lane = tid & 63;
  const int wave = tid >> 6;
  const int m0 = blockIdx.y * 128;
  const int n0 = blockIdx.x * 128;
  const int wm = (wave & 1) * 64;
  const int wn = (wave >> 1) * 64;
  const int lrow = lane & 15;
  const int quad = lane >> 4;

  f32x4 zero = {0.f, 0.f, 0.f, 0.f};
  f32x4 acc[4][4];
#pragma unroll
  for (int i = 0; i < 4; ++i)
#pragma unroll
    for (int j = 0; j < 4; ++j) acc[i][j] = zero;

  for (int kb = 0; kb < K; kb += 64) {
    uint4 ra[4], rb[4];
#pragma unroll
    for (int i = 0; i < 4; ++i) {
      int c = i * 256 + tid;
      int row = c >> 3;
      int cc = (c & 7) * 8;
      ra[i] = *(const uint4*)(A + (size_t)(m0 + row) * K + kb + cc);
      rb[i] = *(const uint4*)(Bt + (size_t)(n0 + row) * K + kb + cc);
    }
    __syncthreads();
#pragma unroll
    for (int i = 0; i < 4; ++i) {
      int c = i * 256 + tid;
      *(uint4*)(sA + c * 8) = ra[i];
      *(uint4*)(sB + c * 8) = rb[i];
    }
    __syncthreads();
#pragma unroll
    for (int ks = 0; ks < 2; ++ks) {
      bf16x8 af[4], bfr[4];
#pragma unroll
      for (int i = 0; i < 4; ++i)
        af[i] = *(const bf16x8*)(sA + (wm + i * 16 + lrow) * 64 + ks * 32 + quad * 8);
#pragma unroll
      for (int j = 0; j < 4; ++j)
        bfr[j] = *(const bf16x8*)(sB + (wn + j * 16 + lrow) * 64 + ks * 32 + quad * 8);
#pragma unroll
      for (int i = 0; i < 4; ++i)
#pragma unroll
        for (int j = 0; j < 4; ++j)
          acc[i][j] = __builtin_amdgcn_mfma_f32_16x16x32_bf16(af[i], bfr[j], acc[i][j], 0, 0, 0);
    }
  }

#pragma unroll
  for (int i = 0; i < 4; ++i) {
    int row = m0 + wm + i * 16 + quad * 4;
#pragma unroll
    for (int j = 0; j < 4; ++j) {
      int col = n0 + wn + j * 16 + lrow;
      float bvv = bias[col];
#pragma unroll
      for (int r = 0; r < 4; ++r)
        C[(size_t)(row + r) * N + col] = acc[i][j][r] + bvv;
    }
  }
}

// ---------------- kv accumulation: kv[bh,kk,vv] += sum_n K[n,kk]*V[n,vv] ----------------
__global__ __launch_bounds__(256) void kv_accum(const bf16_t* __restrict__ kp,
                                                const bf16_t* __restrict__ vp,
                                                float* __restrict__ kv) {
  int bx = blockIdx.x;
  int chunk = bx & 15;
  int bh = bx >> 4;
  int b = bh >> 4, h = bh & 15;
  __shared__ float sK[64][68];
  __shared__ float sV[64][68];
  int tid = threadIdx.x;
  int ty = tid >> 4, tx = tid & 15;
  float acc[4][4] = {};
  int r = tid >> 2;
  int col0 = (tid & 3) * 16;
  int n_base = chunk * 256;

  for (int cc = 0; cc < 4; ++cc) {
    size_t gbase = ((size_t)(b * SEQ + n_base + cc * 64 + r)) * DMODEL + h * 64 + col0;
    bf16x8 k1 = *(const bf16x8*)(kp + gbase);
    bf16x8 k2 = *(const bf16x8*)(kp + gbase + 8);
    bf16x8 v1 = *(const bf16x8*)(vp + gbase);
    bf16x8 v2 = *(const bf16x8*)(vp + gbase + 8);
    __syncthreads();
#pragma unroll
    for (int i = 0; i < 8; ++i) {
      sK[r][col0 + i] = (float)k1[i];
      sK[r][col0 + 8 + i] = (float)k2[i];
      sV[r][col0 + i] = (float)v1[i];
      sV[r][col0 + 8 + i] = (float)v2[i];
    }
    __syncthreads();
#pragma unroll 4
    for (int n = 0; n < 64; ++n) {
      float4 av = *(const float4*)&sK[n][ty * 4];
      float4 bvv = *(const float4*)&sV[n][tx * 4];
      acc[0][0] += av.x * bvv.x; acc[0][1] += av.x * bvv.y; acc[0][2] += av.x * bvv.z; acc[0][3] += av.x * bvv.w;
      acc[1][0] += av.y * bvv.x; acc[1][1] += av.y * bvv.y; acc[1][2] += av.y * bvv.z; acc[1][3] += av.y * bvv.w;
      acc[2][0] += av.z * bvv.x; acc[2][1] += av.z * bvv.y; acc[2][2] += av.z * bvv.z; acc[2][3] += av.z * bvv.w;
      acc[3][0] += av.w * bvv.x; acc[3][1] += av.w * bvv.y; acc[3][2] += av.w * bvv.z; acc[3][3] += av.w * bvv.w;
    }
  }
  float* dst = kv + (size_t)bh * 64 * 64;
#pragma unroll
  for (int i = 0; i < 4; ++i)
#pragma unroll
    for (int j = 0; j < 4; ++j)
      atomicAdd(&dst[(ty * 4 + i) * 64 + (tx * 4 + j)], acc[i][j]);
}

// ---------------- kv normalization + transpose: kv[bh,kk,:] -> kvnT[bh,vv,kk] bf16 ----------------
__global__ __launch_bounds__(64) void kvnorm_kernel(const float* __restrict__ kv,
                                                    const float* __restrict__ gamma,
                                                    bf16_t* __restrict__ kvnT) {
  int bh = blockIdx.x;
  int h = bh & 15;
  int kk = threadIdx.x;  // 0..63
  const float* src = kv + ((size_t)bh * 64 + kk) * 64;
  float vals[64];
  float ss = 0.f;
#pragma unroll
  for (int v = 0; v < 64; ++v) {
    vals[v] = src[v];
    ss += vals[v] * vals[v];
  }
  float scale = gamma[h] * rsqrtf(ss);
  bf16_t* dst = kvnT + (size_t)bh * 64 * 64;
#pragma unroll
  for (int v = 0; v < 64; ++v) dst[v * 64 + kk] = (bf16_t)(vals[v] * scale);
}

// ---------------- attention apply: att[b,n,h*64+vv] = sum_kk qn[bh,n,kk]*kvnT[bh,vv,kk] ----------------
__global__ __launch_bounds__(256) void attn_gemm(const bf16_t* __restrict__ qn,
                                                 const bf16_t* __restrict__ kvnT,
                                                 bf16_t* __restrict__ att) {
  int bx = blockIdx.x;          // bh*32 + chunk
  int chunk = bx & 31, bh = bx >> 5;
  int b = bh >> 4, h = bh & 15;
  int tid = threadIdx.x, lane = tid & 63, wave = tid >> 6;
  int lrow = lane & 15, quad = lane >> 4;
  int n0 = chunk * 128 + wave * 32;
  const bf16_t* qbase = qn + (size_t)bh * SEQ * 64;
  const bf16_t* kvb = kvnT + (size_t)bh * 64 * 64;
  f32x4 zero = {0.f, 0.f, 0.f, 0.f};
  f32x4 acc[2][4];
#pragma unroll
  for (int i = 0; i < 2; ++i)
#pragma unroll
    for (int j = 0; j < 4; ++j) acc[i][j] = zero;
#pragma unroll
  for (int ks = 0; ks < 2; ++ks) {
    bf16x8 af[2], bfr[4];
#pragma unroll
    for (int i = 0; i < 2; ++i)
      af[i] = *(const bf16x8*)(qbase + (size_t)(n0 + i * 16 + lrow) * 64 + ks * 32 + quad * 8);
#pragma unroll
    for (int j = 0; j < 4; ++j)
      bfr[j] = *(const bf16x8*)(kvb + (size_t)(j * 16 + lrow) * 64 + ks * 32 + quad * 8);
#pragma unroll
    for (int i = 0; i < 2; ++i)
#pragma unroll
      for (int j = 0; j < 4; ++j)
        acc[i][j] = __builtin_amdgcn_mfma_f32_16x16x32_bf16(af[i], bfr[j], acc[i][j], 0, 0, 0);
  }
#pragma unroll
  for (int i = 0; i < 2; ++i)
#pragma unroll
    for (int j = 0; j < 4; ++j)
#pragma unroll
      for (int r = 0; r < 4; ++r) {
        int n = n0 + i * 16 + quad * 4 + r;
        att[((size_t)(b * SEQ + n)) * DMODEL + h * 64 + j * 16 + lrow] = (bf16_t)acc[i][j][r];
      }
}

// ---------------- launch ----------------
extern "C" void kernel_launch(void* const* d_in, const int* in_sizes, int n_in,
                              void* d_out, int out_size, void* d_ws, size_t ws_size,
                              hipStream_t stream) {
  const float* queries = (const float*)d_in[0];
  const float* keys    = (const float*)d_in[1];
  const float* values  = (const float*)d_in[2];
  const float* Wq = (const float*)d_in[3];
  const float* bq = (const float*)d_in[4];
  const float* Wk = (const float*)d_in[5];
  const float* bk = (const float*)d_in[6];
  const float* Wv = (const float*)d_in[7];
  const float* bv = (const float*)d_in[8];
  const float* Wo = (const float*)d_in[9];
  const float* bo = (const float*)d_in[10];
  const float* gamma = (const float*)d_in[11];

  char* ws = (char*)d_ws;
  size_t off = 0;
  auto alloc = [&](size_t bytes) -> void* {
    void* p = ws + off;
    off = (off + bytes + 255) & ~(size_t)255;
    return p;
  };
  const size_t actN = (size_t)NROWS * DMODEL;
  // total footprint: 8 MB weights + 3x 33.55 MB + 1.5 MB  ~= 110.6 MB
  bf16_t* wqb   = (bf16_t*)alloc((size_t)DMODEL * DMODEL * 2);
  bf16_t* wkb   = (bf16_t*)alloc((size_t)DMODEL * DMODEL * 2);
  bf16_t* wvb   = (bf16_t*)alloc((size_t)DMODEL * DMODEL * 2);
  bf16_t* wob   = (bf16_t*)alloc((size_t)DMODEL * DMODEL * 2);
  bf16_t* kproj = (bf16_t*)alloc(actN * 2);     // aliased by att after kv_accum
  bf16_t* vproj = (bf16_t*)alloc(actN * 2);
  bf16_t* qn    = (bf16_t*)alloc(actN * 2);
  float*  kv    = (float*)alloc((size_t)64 * 64 * 64 * 4);
  bf16_t* kvnT  = (bf16_t*)alloc((size_t)64 * 64 * 64 * 2);
  bf16_t* att   = kproj;  // alias: kproj dead after kv_accum

  // 1) weight conversions + kv zero
  int w8 = DMODEL * DMODEL / 8;
  f2b_kernel<<<w8 / 256, 256, 0, stream>>>(Wq, wqb, w8);
  f2b_kernel<<<w8 / 256, 256, 0, stream>>>(Wk, wkb, w8);
  f2b_kernel<<<w8 / 256, 256, 0, stream>>>(Wv, wvb, w8);
  f2b_kernel<<<w8 / 256, 256, 0, stream>>>(Wo, wob, w8);
  zero_kernel<<<(64 * 64 * 64 / 4) / 256, 256, 0, stream>>>(kv, 64 * 64 * 64 / 4);

  // 2) projections (A fp32 converted in-register); q-proj fuses the xnorm
  dim3 gg(DMODEL / 128, NROWS / 128);
  gemm_a32_bt<true ><<<gg, 256, 0, stream>>>(queries, wqb, bq, nullptr, qn, gamma,
                                             NROWS, DMODEL, DMODEL);
  gemm_a32_bt<false><<<gg, 256, 0, stream>>>(keys, wkb, bk, kproj, nullptr, nullptr,
                                             NROWS, DMODEL, DMODEL);
  gemm_a32_bt<false><<<gg, 256, 0, stream>>>(values, wvb, bv, vproj, nullptr, nullptr,
                                             NROWS, DMODEL, DMODEL);

  // 3) kv accumulation + norm
  kv_accum<<<64 * 16, 256, 0, stream>>>(kproj, vproj, kv);
  kvnorm_kernel<<<64, 64, 0, stream>>>(kv, gamma, kvnT);

  // 4) attention apply (writes att, aliasing kproj)
  attn_gemm<<<64 * 32, 256, 0, stream>>>(qn, kvnT, att);

  // 5) output projection (fp32 out + bias)
  gemm_bt_f32out<<<gg, 256, 0, stream>>>(att, wob, bo, (float*)d_out, NROWS, DMODEL, DMODEL);
}

// Round 3
// 559.643 us; speedup vs baseline: 1.6293x; 1.6293x over previous
//
#include <hip/hip_runtime.h>
#include <hip/hip_bf16.h>
#include <stdint.h>

typedef __bf16 bf16_t;
typedef __bf16 bf16x8 __attribute__((ext_vector_type(8)));
typedef float f32x4 __attribute__((ext_vector_type(4)));

#define SEQ    4096
#define NROWS  16384   // B * N
#define DMODEL 1024
#define NH     16

// async 16B global->LDS DMA. LDS dest is wave-uniform base + lane*16 (m104).
__device__ __forceinline__ void async_cp16(const bf16_t* g, bf16_t* l) {
  __builtin_amdgcn_global_load_lds((const __attribute__((address_space(1))) void*)g,
                                   (__attribute__((address_space(3))) void*)l,
                                   16, 0, 0);
}

// ---------------- fp32 -> bf16 convert (8 elems/thread) ----------------
__global__ __launch_bounds__(256) void f2b_kernel(const float* __restrict__ x,
                                                  bf16_t* __restrict__ y, int n8) {
  int i = blockIdx.x * 256 + threadIdx.x;
  if (i >= n8) return;
  const float4* xp = (const float4*)x + (size_t)i * 2;
  float4 a = xp[0], b = xp[1];
  bf16x8 o;
  o[0] = (bf16_t)a.x; o[1] = (bf16_t)a.y; o[2] = (bf16_t)a.z; o[3] = (bf16_t)a.w;
  o[4] = (bf16_t)b.x; o[5] = (bf16_t)b.y; o[6] = (bf16_t)b.z; o[7] = (bf16_t)b.w;
  *((bf16x8*)y + i) = o;
}

// ---------------- zero kv ----------------
__global__ __launch_bounds__(256) void zero_kernel(float* __restrict__ p, int n4) {
  int i = blockIdx.x * 256 + threadIdx.x;
  if (i < n4) ((float4*)p)[i] = make_float4(0.f, 0.f, 0.f, 0.f);
}

// ---------------- m97-style GEMM: C[m,n] = sum_k A[m,k]*Bt[n,k] + bias[n] ----------------
// 128x128 tile, BK=64, 4 waves, global_load_lds width-16 staging, 2-barrier K-loop.
// MODE 0: bf16 C   MODE 1: fp32 C   MODE 2: fused q-xnorm -> qn[(b*NH+h)*SEQ+n][kk]
template <int MODE>
__global__ __launch_bounds__(256) void gemm_bt(const bf16_t* __restrict__ A,
                                               const bf16_t* __restrict__ Bt,
                                               const float* __restrict__ bias,
                                               void* __restrict__ Cout,
                                               const float* __restrict__ gamma,
                                               int M, int N, int K) {
  __shared__ bf16_t sA[128 * 64];
  __shared__ bf16_t sB[128 * 64];
  const int tid  = threadIdx.x;
  const int lane = tid & 63;
  const int wave = tid >> 6;
  const int m0 = blockIdx.y * 128;
  const int n0 = blockIdx.x * 128;
  const int wm = (wave & 1) * 64;
  const int wn = (wave >> 1) * 64;
  const int lrow = lane & 15;
  const int quad = lane >> 4;

  // staging geometry: chunk c = it*256 + wave*64 + lane; row=c>>3, col16=c&7.
  // LDS byte addr = c*16 = (it*256+wave*64)*16 + lane*16  -> uniform base + lane*16.
  const int srow = (wave << 3) + (lane >> 3);   // row within the 32-row it-group
  const int scol = (lane & 7) * 8;              // element col of this 16B chunk
  bf16_t* ldsA = sA + (size_t)(wave << 9);      // (wave*64)*8 elems
  bf16_t* ldsB = sB + (size_t)(wave << 9);

  f32x4 zero = {0.f, 0.f, 0.f, 0.f};
  f32x4 acc[4][4];
#pragma unroll
  for (int i = 0; i < 4; ++i)
#pragma unroll
    for (int j = 0; j < 4; ++j) acc[i][j] = zero;

  const bf16_t* Abase = A + (size_t)(m0 + srow) * K + scol;
  const bf16_t* Bbase = Bt + (size_t)(n0 + srow) * K + scol;

  for (int kb = 0; kb < K; kb += 64) {
    __syncthreads();   // previous MFMA fragment reads done before DMA overwrites LDS
#pragma unroll
    for (int it = 0; it < 4; ++it) {
      async_cp16(Abase + kb + (size_t)(it * 32) * K, ldsA + it * 2048);
      async_cp16(Bbase + kb + (size_t)(it * 32) * K, ldsB + it * 2048);
    }
    __syncthreads();   // compiler drains vmcnt before barrier -> DMA landed
#pragma unroll
    for (int ks = 0; ks < 2; ++ks) {
      bf16x8 af[4], bfr[4];
#pragma unroll
      for (int i = 0; i < 4; ++i)
        af[i] = *(const bf16x8*)(sA + (wm + i * 16 + lrow) * 64 + ks * 32 + quad * 8);
#pragma unroll
      for (int j = 0; j < 4; ++j)
        bfr[j] = *(const bf16x8*)(sB + (wn + j * 16 + lrow) * 64 + ks * 32 + quad * 8);
#pragma unroll
      for (int i = 0; i < 4; ++i)
#pragma unroll
        for (int j = 0; j < 4; ++j)
          acc[i][j] = __builtin_amdgcn_mfma_f32_16x16x32_bf16(af[i], bfr[j], acc[i][j], 0, 0, 0);
    }
  }

  float bv[4];
#pragma unroll
  for (int j = 0; j < 4; ++j) bv[j] = bias[n0 + wn + j * 16 + lrow];

  if constexpr (MODE == 2) {
    const int h = (n0 + wn) >> 6;   // wave strip == one head (64 cols)
    const float g = gamma[h];
    bf16_t* qn = (bf16_t*)Cout;
#pragma unroll
    for (int i = 0; i < 4; ++i) {
#pragma unroll
      for (int r = 0; r < 4; ++r) {
        float val[4];
        float ss = 0.f;
#pragma unroll
        for (int j = 0; j < 4; ++j) {
          val[j] = acc[i][j][r] + bv[j];
          ss += val[j] * val[j];
        }
        ss += __shfl_xor(ss, 1);
        ss += __shfl_xor(ss, 2);
        ss += __shfl_xor(ss, 4);
        ss += __shfl_xor(ss, 8);
        float scale = g * rsqrtf(ss);
        int row = m0 + wm + i * 16 + quad * 4 + r;
        int b_ = row >> 12, n = row & (SEQ - 1);
        bf16_t* dst = qn + ((size_t)(b_ * NH + h) * SEQ + n) * 64;
#pragma unroll
        for (int j = 0; j < 4; ++j) dst[j * 16 + lrow] = (bf16_t)(val[j] * scale);
      }
    }
  } else if constexpr (MODE == 1) {
    float* C = (float*)Cout;
#pragma unroll
    for (int i = 0; i < 4; ++i) {
      int row = m0 + wm + i * 16 + quad * 4;
#pragma unroll
      for (int j = 0; j < 4; ++j) {
        int col = n0 + wn + j * 16 + lrow;
#pragma unroll
        for (int r = 0; r < 4; ++r)
          C[(size_t)(row + r) * N + col] = acc[i][j][r] + bv[j];
      }
    }
  } else {
    bf16_t* C = (bf16_t*)Cout;
#pragma unroll
    for (int i = 0; i < 4; ++i) {
      int row = m0 + wm + i * 16 + quad * 4;
#pragma unroll
      for (int j = 0; j < 4; ++j) {
        int col = n0 + wn + j * 16 + lrow;
#pragma unroll
        for (int r = 0; r < 4; ++r)
          C[(size_t)(row + r) * N + col] = (bf16_t)(acc[i][j][r] + bv[j]);
      }
    }
  }
}

// ---------------- kv accumulation: kv[bh,kk,vv] += sum_n K[n,kk]*V[n,vv] ----------------
__global__ __launch_bounds__(256) void kv_accum(const bf16_t* __restrict__ kp,
                                                const bf16_t* __restrict__ vp,
                                                float* __restrict__ kv) {
  int bx = blockIdx.x;
  int chunk = bx & 15;
  int bh = bx >> 4;
  int b = bh >> 4, h = bh & 15;
  __shared__ float sK[64][68];
  __shared__ float sV[64][68];
  int tid = threadIdx.x;
  int ty = tid >> 4, tx = tid & 15;
  float acc[4][4] = {};
  int r = tid >> 2;
  int col0 = (tid & 3) * 16;
  int n_base = chunk * 256;

  for (int cc = 0; cc < 4; ++cc) {
    size_t gbase = ((size_t)(b * SEQ + n_base + cc * 64 + r)) * DMODEL + h * 64 + col0;
    bf16x8 k1 = *(const bf16x8*)(kp + gbase);
    bf16x8 k2 = *(const bf16x8*)(kp + gbase + 8);
    bf16x8 v1 = *(const bf16x8*)(vp + gbase);
    bf16x8 v2 = *(const bf16x8*)(vp + gbase + 8);
    __syncthreads();
#pragma unroll
    for (int i = 0; i < 8; ++i) {
      sK[r][col0 + i] = (float)k1[i];
      sK[r][col0 + 8 + i] = (float)k2[i];
      sV[r][col0 + i] = (float)v1[i];
      sV[r][col0 + 8 + i] = (float)v2[i];
    }
    __syncthreads();
#pragma unroll 4
    for (int n = 0; n < 64; ++n) {
      float4 av = *(const float4*)&sK[n][ty * 4];
      float4 bvv = *(const float4*)&sV[n][tx * 4];
      acc[0][0] += av.x * bvv.x; acc[0][1] += av.x * bvv.y; acc[0][2] += av.x * bvv.z; acc[0][3] += av.x * bvv.w;
      acc[1][0] += av.y * bvv.x; acc[1][1] += av.y * bvv.y; acc[1][2] += av.y * bvv.z; acc[1][3] += av.y * bvv.w;
      acc[2][0] += av.z * bvv.x; acc[2][1] += av.z * bvv.y; acc[2][2] += av.z * bvv.z; acc[2][3] += av.z * bvv.w;
      acc[3][0] += av.w * bvv.x; acc[3][1] += av.w * bvv.y; acc[3][2] += av.w * bvv.z; acc[3][3] += av.w * bvv.w;
    }
  }
  float* dst = kv + (size_t)bh * 64 * 64;
#pragma unroll
  for (int i = 0; i < 4; ++i)
#pragma unroll
    for (int j = 0; j < 4; ++j)
      atomicAdd(&dst[(ty * 4 + i) * 64 + (tx * 4 + j)], acc[i][j]);
}

// ---------------- kv normalization + transpose: kv[bh,kk,:] -> kvnT[bh,vv,kk] bf16 ----------------
__global__ __launch_bounds__(64) void kvnorm_kernel(const float* __restrict__ kv,
                                                    const float* __restrict__ gamma,
                                                    bf16_t* __restrict__ kvnT) {
  int bh = blockIdx.x;
  int h = bh & 15;
  int kk = threadIdx.x;  // 0..63
  const float* src = kv + ((size_t)bh * 64 + kk) * 64;
  float vals[64];
  float ss = 0.f;
#pragma unroll
  for (int v = 0; v < 64; ++v) {
    vals[v] = src[v];
    ss += vals[v] * vals[v];
  }
  float scale = gamma[h] * rsqrtf(ss);
  bf16_t* dst = kvnT + (size_t)bh * 64 * 64;
#pragma unroll
  for (int v = 0; v < 64; ++v) dst[v * 64 + kk] = (bf16_t)(vals[v] * scale);
}

// ---------------- attention apply: att[b,n,h*64+vv] = sum_kk qn[bh,n,kk]*kvnT[bh,vv,kk] ----------------
__global__ __launch_bounds__(256) void attn_gemm(const bf16_t* __restrict__ qn,
                                                 const bf16_t* __restrict__ kvnT,
                                                 bf16_t* __restrict__ att) {
  int bx = blockIdx.x;          // bh*32 + chunk
  int chunk = bx & 31, bh = bx >> 5;
  int b = bh >> 4, h = bh & 15;
  int tid = threadIdx.x, lane = tid & 63, wave = tid >> 6;
  int lrow = lane & 15, quad = lane >> 4;
  int n0 = chunk * 128 + wave * 32;
  const bf16_t* qbase = qn + (size_t)bh * SEQ * 64;
  const bf16_t* kvb = kvnT + (size_t)bh * 64 * 64;
  f32x4 zero = {0.f, 0.f, 0.f, 0.f};
  f32x4 acc[2][4];
#pragma unroll
  for (int i = 0; i < 2; ++i)
#pragma unroll
    for (int j = 0; j < 4; ++j) acc[i][j] = zero;
#pragma unroll
  for (int ks = 0; ks < 2; ++ks) {
    bf16x8 af[2], bfr[4];
#pragma unroll
    for (int i = 0; i < 2; ++i)
      af[i] = *(const bf16x8*)(qbase + (size_t)(n0 + i * 16 + lrow) * 64 + ks * 32 + quad * 8);
#pragma unroll
    for (int j = 0; j < 4; ++j)
      bfr[j] = *(const bf16x8*)(kvb + (size_t)(j * 16 + lrow) * 64 + ks * 32 + quad * 8);
#pragma unroll
    for (int i = 0; i < 2; ++i)
#pragma unroll
      for (int j = 0; j < 4; ++j)
        acc[i][j] = __builtin_amdgcn_mfma_f32_16x16x32_bf16(af[i], bfr[j], acc[i][j], 0, 0, 0);
  }
#pragma unroll
  for (int i = 0; i < 2; ++i)
#pragma unroll
    for (int j = 0; j < 4; ++j)
#pragma unroll
      for (int r = 0; r < 4; ++r) {
        int n = n0 + i * 16 + quad * 4 + r;
        att[((size_t)(b * SEQ + n)) * DMODEL + h * 64 + j * 16 + lrow] = (bf16_t)acc[i][j][r];
      }
}

// ---------------- launch ----------------
extern "C" void kernel_launch(void* const* d_in, const int* in_sizes, int n_in,
                              void* d_out, int out_size, void* d_ws, size_t ws_size,
                              hipStream_t stream) {
  const float* queries = (const float*)d_in[0];
  const float* keys    = (const float*)d_in[1];
  const float* values  = (const float*)d_in[2];
  const float* Wq = (const float*)d_in[3];
  const float* bq = (const float*)d_in[4];
  const float* Wk = (const float*)d_in[5];
  const float* bk = (const float*)d_in[6];
  const float* Wv = (const float*)d_in[7];
  const float* bv = (const float*)d_in[8];
  const float* Wo = (const float*)d_in[9];
  const float* bo = (const float*)d_in[10];
  const float* gamma = (const float*)d_in[11];

  char* ws = (char*)d_ws;
  size_t off = 0;
  auto alloc = [&](size_t bytes) -> void* {
    void* p = ws + off;
    off = (off + bytes + 255) & ~(size_t)255;
    return p;
  };
  const size_t actN = (size_t)NROWS * DMODEL;
  // footprint: 8 MB weights + 3 x 33.55 MB act + 1.5 MB = 110.6 MB (round-1-proven size)
  bf16_t* wqb  = (bf16_t*)alloc((size_t)DMODEL * DMODEL * 2);
  bf16_t* wkb  = (bf16_t*)alloc((size_t)DMODEL * DMODEL * 2);
  bf16_t* wvb  = (bf16_t*)alloc((size_t)DMODEL * DMODEL * 2);
  bf16_t* wob  = (bf16_t*)alloc((size_t)DMODEL * DMODEL * 2);
  bf16_t* actb = (bf16_t*)alloc(actN * 2);   // rotating bf16 A-operand buffer
  bf16_t* bufA = (bf16_t*)alloc(actN * 2);   // kproj, later qn
  bf16_t* bufB = (bf16_t*)alloc(actN * 2);   // vproj, later att
  float*  kv   = (float*)alloc((size_t)64 * 64 * 64 * 4);
  bf16_t* kvnT = (bf16_t*)alloc((size_t)64 * 64 * 64 * 2);

  int w8 = DMODEL * DMODEL / 8;
  int act8 = (int)(actN / 8);
  dim3 gg(DMODEL / 128, NROWS / 128);

  // weights + kv zero
  f2b_kernel<<<w8 / 256, 256, 0, stream>>>(Wk, wkb, w8);
  f2b_kernel<<<w8 / 256, 256, 0, stream>>>(Wv, wvb, w8);
  f2b_kernel<<<w8 / 256, 256, 0, stream>>>(Wq, wqb, w8);
  f2b_kernel<<<w8 / 256, 256, 0, stream>>>(Wo, wob, w8);
  zero_kernel<<<(64 * 64 * 64 / 4) / 256, 256, 0, stream>>>(kv, 64 * 64 * 64 / 4);

  // K projection
  f2b_kernel<<<act8 / 256, 256, 0, stream>>>(keys, actb, act8);
  gemm_bt<0><<<gg, 256, 0, stream>>>(actb, wkb, bk, bufA, nullptr, NROWS, DMODEL, DMODEL);
  // V projection
  f2b_kernel<<<act8 / 256, 256, 0, stream>>>(values, actb, act8);
  gemm_bt<0><<<gg, 256, 0, stream>>>(actb, wvb, bv, bufB, nullptr, NROWS, DMODEL, DMODEL);

  // kv accumulation + norm (kproj=bufA, vproj=bufB die after this)
  kv_accum<<<64 * 16, 256, 0, stream>>>(bufA, bufB, kv);
  kvnorm_kernel<<<64, 64, 0, stream>>>(kv, gamma, kvnT);

  // Q projection with fused xnorm -> qn (into bufA, dead kproj)
  f2b_kernel<<<act8 / 256, 256, 0, stream>>>(queries, actb, act8);
  gemm_bt<2><<<gg, 256, 0, stream>>>(actb, wqb, bq, bufA, gamma, NROWS, DMODEL, DMODEL);

  // attention apply -> att (into bufB, dead vproj)
  attn_gemm<<<64 * 32, 256, 0, stream>>>(bufA, kvnT, bufB);

  // output projection (fp32 out + bias)
  gemm_bt<1><<<gg, 256, 0, stream>>>(bufB, wob, bo, d_out, nullptr, NROWS, DMODEL, DMODEL);
}

// Round 4
// 511.707 us; speedup vs baseline: 1.7819x; 1.0937x over previous
//
#include <hip/hip_runtime.h>
#include <hip/hip_bf16.h>
#include <stdint.h>

typedef __bf16 bf16_t;
typedef __bf16 bf16x8 __attribute__((ext_vector_type(8)));
typedef float f32x4 __attribute__((ext_vector_type(4)));

#define SEQ    4096
#define NROWS  16384   // B * N
#define DMODEL 1024
#define NH     16

// async 16B global->LDS DMA. LDS dest is wave-uniform base + lane*16 (m104).
__device__ __forceinline__ void async_cp16(const bf16_t* g, bf16_t* l) {
  __builtin_amdgcn_global_load_lds((const __attribute__((address_space(1))) void*)g,
                                   (__attribute__((address_space(3))) void*)l,
                                   16, 0, 0);
}

// ---------------- fp32 -> bf16 convert (8 elems/thread) ----------------
__global__ __launch_bounds__(256) void f2b_kernel(const float* __restrict__ x,
                                                  bf16_t* __restrict__ y, int n8) {
  int i = blockIdx.x * 256 + threadIdx.x;
  if (i >= n8) return;
  const float4* xp = (const float4*)x + (size_t)i * 2;
  float4 a = xp[0], b = xp[1];
  bf16x8 o;
  o[0] = (bf16_t)a.x; o[1] = (bf16_t)a.y; o[2] = (bf16_t)a.z; o[3] = (bf16_t)a.w;
  o[4] = (bf16_t)b.x; o[5] = (bf16_t)b.y; o[6] = (bf16_t)b.z; o[7] = (bf16_t)b.w;
  *((bf16x8*)y + i) = o;
}

// all 4 weight matrices in one dispatch (blockIdx.y selects tensor)
__global__ __launch_bounds__(256) void f2b4_kernel(const float* __restrict__ x0, bf16_t* __restrict__ y0,
                                                   const float* __restrict__ x1, bf16_t* __restrict__ y1,
                                                   const float* __restrict__ x2, bf16_t* __restrict__ y2,
                                                   const float* __restrict__ x3, bf16_t* __restrict__ y3,
                                                   int n8) {
  int i = blockIdx.x * 256 + threadIdx.x;
  if (i >= n8) return;
  const float* x = (blockIdx.y == 0) ? x0 : (blockIdx.y == 1) ? x1 : (blockIdx.y == 2) ? x2 : x3;
  bf16_t* y = (blockIdx.y == 0) ? y0 : (blockIdx.y == 1) ? y1 : (blockIdx.y == 2) ? y2 : y3;
  const float4* xp = (const float4*)x + (size_t)i * 2;
  float4 a = xp[0], b = xp[1];
  bf16x8 o;
  o[0] = (bf16_t)a.x; o[1] = (bf16_t)a.y; o[2] = (bf16_t)a.z; o[3] = (bf16_t)a.w;
  o[4] = (bf16_t)b.x; o[5] = (bf16_t)b.y; o[6] = (bf16_t)b.z; o[7] = (bf16_t)b.w;
  *((bf16x8*)y + i) = o;
}

// ---------------- zero kv ----------------
__global__ __launch_bounds__(256) void zero_kernel(float* __restrict__ p, int n4) {
  int i = blockIdx.x * 256 + threadIdx.x;
  if (i < n4) ((float4*)p)[i] = make_float4(0.f, 0.f, 0.f, 0.f);
}

// ---------------- m97-style GEMM + XOR-swizzled LDS + XCD-aware block decode ----------------
// C[m,n] = sum_k A[m,k]*Bt[n,k] + bias[n]; 128x128 tile, BK=64, 4 waves.
// LDS: physical 16B-chunk cpos of row holds logical chunk (cpos ^ (row&7)).
// Grid: 1D, 1024 blocks. id&7 = XCD slot; 16-row A-band per XCD, N-block fastest.
// MODE 0: bf16 C   MODE 1: fp32 C   MODE 2: fused q-xnorm -> qn[(b*NH+h)*SEQ+n][kk]
template <int MODE>
__global__ __launch_bounds__(256) void gemm_bt(const bf16_t* __restrict__ A,
                                               const bf16_t* __restrict__ Bt,
                                               const float* __restrict__ bias,
                                               void* __restrict__ Cout,
                                               const float* __restrict__ gamma,
                                               int M, int N, int K) {
  __shared__ bf16_t sA[128 * 64];
  __shared__ bf16_t sB[128 * 64];
  const int tid  = threadIdx.x;
  const int lane = tid & 63;
  const int wave = tid >> 6;

  // XCD-aware decode: xcd = id&7 (round-robin heuristic), x fastest within XCD.
  const int id  = blockIdx.x;
  const int xcd = id & 7;
  const int kk_ = id >> 3;                 // 0..127
  const int bx  = kk_ & 7;                 // N block (8 total)
  const int by  = (xcd << 4) | (kk_ >> 3); // 16-row band per XCD
  const int m0 = by * 128;
  const int n0 = bx * 128;

  const int wm = (wave & 1) * 64;
  const int wn = (wave >> 1) * 64;
  const int lrow = lane & 15;
  const int quad = lane >> 4;

  // staging: slot s = it*256 + wave*64 + lane; row = s>>3, cpos = lane&7.
  // row&7 == lane>>3, so source chunk = (lane&7) ^ (lane>>3)  (XOR swizzle).
  const int srow = (wave << 3) + (lane >> 3);
  const int scol = (((lane & 7) ^ (lane >> 3)) * 8);
  bf16_t* ldsA = sA + (size_t)(wave << 9);
  bf16_t* ldsB = sB + (size_t)(wave << 9);

  f32x4 zero = {0.f, 0.f, 0.f, 0.f};
  f32x4 acc[4][4];
#pragma unroll
  for (int i = 0; i < 4; ++i)
#pragma unroll
    for (int j = 0; j < 4; ++j) acc[i][j] = zero;

  const bf16_t* Abase = A + (size_t)(m0 + srow) * K + scol;
  const bf16_t* Bbase = Bt + (size_t)(n0 + srow) * K + scol;
  const int swz = lrow;  // row&7 == lrow&7 for fragment rows (wm,i*16 are mult of 8)

  for (int kb = 0; kb < K; kb += 64) {
    __syncthreads();   // previous fragment reads done before DMA overwrites LDS
#pragma unroll
    for (int it = 0; it < 4; ++it) {
      async_cp16(Abase + kb + (size_t)(it * 32) * K, ldsA + it * 2048);
      async_cp16(Bbase + kb + (size_t)(it * 32) * K, ldsB + it * 2048);
    }
    __syncthreads();   // vmcnt drained before barrier -> DMA landed
#pragma unroll
    for (int ks = 0; ks < 2; ++ks) {
      bf16x8 af[4], bfr[4];
#pragma unroll
      for (int i = 0; i < 4; ++i)
        af[i] = *(const bf16x8*)(sA + (wm + i * 16 + lrow) * 64 +
                                 (((ks * 4 + quad) ^ (swz & 7)) * 8));
#pragma unroll
      for (int j = 0; j < 4; ++j)
        bfr[j] = *(const bf16x8*)(sB + (wn + j * 16 + lrow) * 64 +
                                  (((ks * 4 + quad) ^ (swz & 7)) * 8));
#pragma unroll
      for (int i = 0; i < 4; ++i)
#pragma unroll
        for (int j = 0; j < 4; ++j)
          acc[i][j] = __builtin_amdgcn_mfma_f32_16x16x32_bf16(af[i], bfr[j], acc[i][j], 0, 0, 0);
    }
  }

  float bv[4];
#pragma unroll
  for (int j = 0; j < 4; ++j) bv[j] = bias[n0 + wn + j * 16 + lrow];

  if constexpr (MODE == 2) {
    const int h = (n0 + wn) >> 6;   // wave strip == one head (64 cols)
    const float g = gamma[h];
    bf16_t* qn = (bf16_t*)Cout;
#pragma unroll
    for (int i = 0; i < 4; ++i) {
#pragma unroll
      for (int r = 0; r < 4; ++r) {
        float val[4];
        float ss = 0.f;
#pragma unroll
        for (int j = 0; j < 4; ++j) {
          val[j] = acc[i][j][r] + bv[j];
          ss += val[j] * val[j];
        }
        ss += __shfl_xor(ss, 1);
        ss += __shfl_xor(ss, 2);
        ss += __shfl_xor(ss, 4);
        ss += __shfl_xor(ss, 8);
        float scale = g * rsqrtf(ss);
        int row = m0 + wm + i * 16 + quad * 4 + r;
        int b_ = row >> 12, n = row & (SEQ - 1);
        bf16_t* dst = qn + ((size_t)(b_ * NH + h) * SEQ + n) * 64;
#pragma unroll
        for (int j = 0; j < 4; ++j) dst[j * 16 + lrow] = (bf16_t)(val[j] * scale);
      }
    }
  } else if constexpr (MODE == 1) {
    float* C = (float*)Cout;
#pragma unroll
    for (int i = 0; i < 4; ++i) {
      int row = m0 + wm + i * 16 + quad * 4;
#pragma unroll
      for (int j = 0; j < 4; ++j) {
        int col = n0 + wn + j * 16 + lrow;
#pragma unroll
        for (int r = 0; r < 4; ++r)
          C[(size_t)(row + r) * N + col] = acc[i][j][r] + bv[j];
      }
    }
  } else {
    bf16_t* C = (bf16_t*)Cout;
#pragma unroll
    for (int i = 0; i < 4; ++i) {
      int row = m0 + wm + i * 16 + quad * 4;
#pragma unroll
      for (int j = 0; j < 4; ++j) {
        int col = n0 + wn + j * 16 + lrow;
#pragma unroll
        for (int r = 0; r < 4; ++r)
          C[(size_t)(row + r) * N + col] = (bf16_t)(acc[i][j][r] + bv[j]);
      }
    }
  }
}

// ---------------- kv accumulation: kv[bh,kk,vv] += sum_n K[n,kk]*V[n,vv] ----------------
__global__ __launch_bounds__(256) void kv_accum(const bf16_t* __restrict__ kp,
                                                const bf16_t* __restrict__ vp,
                                                float* __restrict__ kv) {
  int bx = blockIdx.x;
  int chunk = bx & 15;
  int bh = bx >> 4;
  int b = bh >> 4, h = bh & 15;
  __shared__ float sK[64][68];
  __shared__ float sV[64][68];
  int tid = threadIdx.x;
  int ty = tid >> 4, tx = tid & 15;
  float acc[4][4] = {};
  int r = tid >> 2;
  int col0 = (tid & 3) * 16;
  int n_base = chunk * 256;

  for (int cc = 0; cc < 4; ++cc) {
    size_t gbase = ((size_t)(b * SEQ + n_base + cc * 64 + r)) * DMODEL + h * 64 + col0;
    bf16x8 k1 = *(const bf16x8*)(kp + gbase);
    bf16x8 k2 = *(const bf16x8*)(kp + gbase + 8);
    bf16x8 v1 = *(const bf16x8*)(vp + gbase);
    bf16x8 v2 = *(const bf16x8*)(vp + gbase + 8);
    __syncthreads();
#pragma unroll
    for (int i = 0; i < 8; ++i) {
      sK[r][col0 + i] = (float)k1[i];
      sK[r][col0 + 8 + i] = (float)k2[i];
      sV[r][col0 + i] = (float)v1[i];
      sV[r][col0 + 8 + i] = (float)v2[i];
    }
    __syncthreads();
#pragma unroll 4
    for (int n = 0; n < 64; ++n) {
      float4 av = *(const float4*)&sK[n][ty * 4];
      float4 bvv = *(const float4*)&sV[n][tx * 4];
      acc[0][0] += av.x * bvv.x; acc[0][1] += av.x * bvv.y; acc[0][2] += av.x * bvv.z; acc[0][3] += av.x * bvv.w;
      acc[1][0] += av.y * bvv.x; acc[1][1] += av.y * bvv.y; acc[1][2] += av.y * bvv.z; acc[1][3] += av.y * bvv.w;
      acc[2][0] += av.z * bvv.x; acc[2][1] += av.z * bvv.y; acc[2][2] += av.z * bvv.z; acc[2][3] += av.z * bvv.w;
      acc[3][0] += av.w * bvv.x; acc[3][1] += av.w * bvv.y; acc[3][2] += av.w * bvv.z; acc[3][3] += av.w * bvv.w;
    }
  }
  float* dst = kv + (size_t)bh * 64 * 64;
#pragma unroll
  for (int i = 0; i < 4; ++i)
#pragma unroll
    for (int j = 0; j < 4; ++j)
      atomicAdd(&dst[(ty * 4 + i) * 64 + (tx * 4 + j)], acc[i][j]);
}

// ---------------- kv normalization + transpose: kv[bh,kk,:] -> kvnT[bh,vv,kk] bf16 ----------------
__global__ __launch_bounds__(64) void kvnorm_kernel(const float* __restrict__ kv,
                                                    const float* __restrict__ gamma,
                                                    bf16_t* __restrict__ kvnT) {
  int bh = blockIdx.x;
  int h = bh & 15;
  int kk = threadIdx.x;  // 0..63
  const float* src = kv + ((size_t)bh * 64 + kk) * 64;
  float vals[64];
  float ss = 0.f;
#pragma unroll
  for (int v = 0; v < 64; ++v) {
    vals[v] = src[v];
    ss += vals[v] * vals[v];
  }
  float scale = gamma[h] * rsqrtf(ss);
  bf16_t* dst = kvnT + (size_t)bh * 64 * 64;
#pragma unroll
  for (int v = 0; v < 64; ++v) dst[v * 64 + kk] = (bf16_t)(vals[v] * scale);
}

// ---------------- attention apply: att[b,n,h*64+vv] = sum_kk qn[bh,n,kk]*kvnT[bh,vv,kk] ----------------
__global__ __launch_bounds__(256) void attn_gemm(const bf16_t* __restrict__ qn,
                                                 const bf16_t* __restrict__ kvnT,
                                                 bf16_t* __restrict__ att) {
  int bx = blockIdx.x;          // bh*32 + chunk
  int chunk = bx & 31, bh = bx >> 5;
  int b = bh >> 4, h = bh & 15;
  int tid = threadIdx.x, lane = tid & 63, wave = tid >> 6;
  int lrow = lane & 15, quad = lane >> 4;
  int n0 = chunk * 128 + wave * 32;
  const bf16_t* qbase = qn + (size_t)bh * SEQ * 64;
  const bf16_t* kvb = kvnT + (size_t)bh * 64 * 64;
  f32x4 zero = {0.f, 0.f, 0.f, 0.f};
  f32x4 acc[2][4];
#pragma unroll
  for (int i = 0; i < 2; ++i)
#pragma unroll
    for (int j = 0; j < 4; ++j) acc[i][j] = zero;
#pragma unroll
  for (int ks = 0; ks < 2; ++ks) {
    bf16x8 af[2], bfr[4];
#pragma unroll
    for (int i = 0; i < 2; ++i)
      af[i] = *(const bf16x8*)(qbase + (size_t)(n0 + i * 16 + lrow) * 64 + ks * 32 + quad * 8);
#pragma unroll
    for (int j = 0; j < 4; ++j)
      bfr[j] = *(const bf16x8*)(kvb + (size_t)(j * 16 + lrow) * 64 + ks * 32 + quad * 8);
#pragma unroll
    for (int i = 0; i < 2; ++i)
#pragma unroll
      for (int j = 0; j < 4; ++j)
        acc[i][j] = __builtin_amdgcn_mfma_f32_16x16x32_bf16(af[i], bfr[j], acc[i][j], 0, 0, 0);
  }
#pragma unroll
  for (int i = 0; i < 2; ++i)
#pragma unroll
    for (int j = 0; j < 4; ++j)
#pragma unroll
      for (int r = 0; r < 4; ++r) {
        int n = n0 + i * 16 + quad * 4 + r;
        att[((size_t)(b * SEQ + n)) * DMODEL + h * 64 + j * 16 + lrow] = (bf16_t)acc[i][j][r];
      }
}

// ---------------- launch ----------------
extern "C" void kernel_launch(void* const* d_in, const int* in_sizes, int n_in,
                              void* d_out, int out_size, void* d_ws, size_t ws_size,
                              hipStream_t stream) {
  const float* queries = (const float*)d_in[0];
  const float* keys    = (const float*)d_in[1];
  const float* values  = (const float*)d_in[2];
  const float* Wq = (const float*)d_in[3];
  const float* bq = (const float*)d_in[4];
  const float* Wk = (const float*)d_in[5];
  const float* bk = (const float*)d_in[6];
  const float* Wv = (const float*)d_in[7];
  const float* bv = (const float*)d_in[8];
  const float* Wo = (const float*)d_in[9];
  const float* bo = (const float*)d_in[10];
  const float* gamma = (const float*)d_in[11];

  char* ws = (char*)d_ws;
  size_t off = 0;
  auto alloc = [&](size_t bytes) -> void* {
    void* p = ws + off;
    off = (off + bytes + 255) & ~(size_t)255;
    return p;
  };
  const size_t actN = (size_t)NROWS * DMODEL;
  // footprint: 8 MB weights + 3 x 33.55 MB act + 1.5 MB = 110.6 MB (proven size)
  bf16_t* wqb  = (bf16_t*)alloc((size_t)DMODEL * DMODEL * 2);
  bf16_t* wkb  = (bf16_t*)alloc((size_t)DMODEL * DMODEL * 2);
  bf16_t* wvb  = (bf16_t*)alloc((size_t)DMODEL * DMODEL * 2);
  bf16_t* wob  = (bf16_t*)alloc((size_t)DMODEL * DMODEL * 2);
  bf16_t* actb = (bf16_t*)alloc(actN * 2);   // rotating bf16 A-operand buffer
  bf16_t* bufA = (bf16_t*)alloc(actN * 2);   // kproj, later qn
  bf16_t* bufB = (bf16_t*)alloc(actN * 2);   // vproj, later att
  float*  kv   = (float*)alloc((size_t)64 * 64 * 64 * 4);
  bf16_t* kvnT = (bf16_t*)alloc((size_t)64 * 64 * 64 * 2);

  int w8 = DMODEL * DMODEL / 8;
  int act8 = (int)(actN / 8);
  const int gemm_grid = (NROWS / 128) * (DMODEL / 128);  // 1024, 1D + internal decode

  // weights (one dispatch) + kv zero
  f2b4_kernel<<<dim3(w8 / 256, 4), 256, 0, stream>>>(Wk, wkb, Wv, wvb, Wq, wqb, Wo, wob, w8);
  zero_kernel<<<(64 * 64 * 64 / 4) / 256, 256, 0, stream>>>(kv, 64 * 64 * 64 / 4);

  // K projection
  f2b_kernel<<<act8 / 256, 256, 0, stream>>>(keys, actb, act8);
  gemm_bt<0><<<gemm_grid, 256, 0, stream>>>(actb, wkb, bk, bufA, nullptr, NROWS, DMODEL, DMODEL);
  // V projection
  f2b_kernel<<<act8 / 256, 256, 0, stream>>>(values, actb, act8);
  gemm_bt<0><<<gemm_grid, 256, 0, stream>>>(actb, wvb, bv, bufB, nullptr, NROWS, DMODEL, DMODEL);

  // kv accumulation + norm (kproj=bufA, vproj=bufB die after this)
  kv_accum<<<64 * 16, 256, 0, stream>>>(bufA, bufB, kv);
  kvnorm_kernel<<<64, 64, 0, stream>>>(kv, gamma, kvnT);

  // Q projection with fused xnorm -> qn (into bufA, dead kproj)
  f2b_kernel<<<act8 / 256, 256, 0, stream>>>(queries, actb, act8);
  gemm_bt<2><<<gemm_grid, 256, 0, stream>>>(actb, wqb, bq, bufA, gamma, NROWS, DMODEL, DMODEL);

  // attention apply -> att (into bufB, dead vproj)
  attn_gemm<<<64 * 32, 256, 0, stream>>>(bufA, kvnT, bufB);

  // output projection (fp32 out + bias)
  gemm_bt<1><<<gemm_grid, 256, 0, stream>>>(bufB, wob, bo, d_out, nullptr, NROWS, DMODEL, DMODEL);
}

// Round 5
// 474.528 us; speedup vs baseline: 1.9215x; 1.0783x over previous
//
#include <hip/hip_runtime.h>
#include <hip/hip_bf16.h>
#include <stdint.h>

typedef __bf16 bf16_t;
typedef __bf16 bf16x8 __attribute__((ext_vector_type(8)));
typedef float f32x4 __attribute__((ext_vector_type(4)));

#define SEQ    4096
#define NROWS  16384   // B * N
#define DMODEL 1024
#define NH     16

// async 16B global->LDS DMA. LDS dest is wave-uniform base + lane*16 (m104).
__device__ __forceinline__ void async_cp16(const bf16_t* g, bf16_t* l) {
  __builtin_amdgcn_global_load_lds((const __attribute__((address_space(1))) void*)g,
                                   (__attribute__((address_space(3))) void*)l,
                                   16, 0, 0);
}

// ---------------- fp32 -> bf16 convert (8 elems/thread) ----------------
__global__ __launch_bounds__(256) void f2b_kernel(const float* __restrict__ x,
                                                  bf16_t* __restrict__ y, int n8) {
  int i = blockIdx.x * 256 + threadIdx.x;
  if (i >= n8) return;
  const float4* xp = (const float4*)x + (size_t)i * 2;
  float4 a = xp[0], b = xp[1];
  bf16x8 o;
  o[0] = (bf16_t)a.x; o[1] = (bf16_t)a.y; o[2] = (bf16_t)a.z; o[3] = (bf16_t)a.w;
  o[4] = (bf16_t)b.x; o[5] = (bf16_t)b.y; o[6] = (bf16_t)b.z; o[7] = (bf16_t)b.w;
  *((bf16x8*)y + i) = o;
}

// 4 weight conversions + kv zero in one dispatch (blockIdx.y selects job)
__global__ __launch_bounds__(256) void f2b4_kernel(const float* __restrict__ x0, bf16_t* __restrict__ y0,
                                                   const float* __restrict__ x1, bf16_t* __restrict__ y1,
                                                   const float* __restrict__ x2, bf16_t* __restrict__ y2,
                                                   const float* __restrict__ x3, bf16_t* __restrict__ y3,
                                                   float* __restrict__ kvz, int kvn4, int n8) {
  int i = blockIdx.x * 256 + threadIdx.x;
  if (blockIdx.y == 4) {
    if (i < kvn4) ((float4*)kvz)[i] = make_float4(0.f, 0.f, 0.f, 0.f);
    return;
  }
  if (i >= n8) return;
  const float* x = (blockIdx.y == 0) ? x0 : (blockIdx.y == 1) ? x1 : (blockIdx.y == 2) ? x2 : x3;
  bf16_t* y = (blockIdx.y == 0) ? y0 : (blockIdx.y == 1) ? y1 : (blockIdx.y == 2) ? y2 : y3;
  const float4* xp = (const float4*)x + (size_t)i * 2;
  float4 a = xp[0], b = xp[1];
  bf16x8 o;
  o[0] = (bf16_t)a.x; o[1] = (bf16_t)a.y; o[2] = (bf16_t)a.z; o[3] = (bf16_t)a.w;
  o[4] = (bf16_t)b.x; o[5] = (bf16_t)b.y; o[6] = (bf16_t)b.z; o[7] = (bf16_t)b.w;
  *((bf16x8*)y + i) = o;
}

// ---------------- m97-style GEMM + XOR-swizzled LDS + XCD-aware block decode ----------------
// C[m,n] = sum_k A[m,k]*Bt[n,k] + bias[n]; 128x128 tile, BK=64, 4 waves.
// MODE 0: bf16 C   MODE 1: fp32 C   MODE 2: fused q-xnorm -> qn[(b*NH+h)*SEQ+n][kk]
template <int MODE>
__global__ __launch_bounds__(256) void gemm_bt(const bf16_t* __restrict__ A,
                                               const bf16_t* __restrict__ Bt,
                                               const float* __restrict__ bias,
                                               void* __restrict__ Cout,
                                               const float* __restrict__ gamma,
                                               int M, int N, int K) {
  __shared__ bf16_t sA[128 * 64];
  __shared__ bf16_t sB[128 * 64];
  const int tid  = threadIdx.x;
  const int lane = tid & 63;
  const int wave = tid >> 6;

  const int id  = blockIdx.x;
  const int xcd = id & 7;
  const int kk_ = id >> 3;                 // 0..127
  const int bx  = kk_ & 7;                 // N block (8 total)
  const int by  = (xcd << 4) | (kk_ >> 3); // 16-row band per XCD
  const int m0 = by * 128;
  const int n0 = bx * 128;

  const int wm = (wave & 1) * 64;
  const int wn = (wave >> 1) * 64;
  const int lrow = lane & 15;
  const int quad = lane >> 4;

  const int srow = (wave << 3) + (lane >> 3);
  const int scol = (((lane & 7) ^ (lane >> 3)) * 8);
  bf16_t* ldsA = sA + (size_t)(wave << 9);
  bf16_t* ldsB = sB + (size_t)(wave << 9);

  f32x4 zero = {0.f, 0.f, 0.f, 0.f};
  f32x4 acc[4][4];
#pragma unroll
  for (int i = 0; i < 4; ++i)
#pragma unroll
    for (int j = 0; j < 4; ++j) acc[i][j] = zero;

  const bf16_t* Abase = A + (size_t)(m0 + srow) * K + scol;
  const bf16_t* Bbase = Bt + (size_t)(n0 + srow) * K + scol;
  const int swz = lrow & 7;

  for (int kb = 0; kb < K; kb += 64) {
    __syncthreads();
#pragma unroll
    for (int it = 0; it < 4; ++it) {
      async_cp16(Abase + kb + (size_t)(it * 32) * K, ldsA + it * 2048);
      async_cp16(Bbase + kb + (size_t)(it * 32) * K, ldsB + it * 2048);
    }
    __syncthreads();
#pragma unroll
    for (int ks = 0; ks < 2; ++ks) {
      bf16x8 af[4], bfr[4];
#pragma unroll
      for (int i = 0; i < 4; ++i)
        af[i] = *(const bf16x8*)(sA + (wm + i * 16 + lrow) * 64 +
                                 (((ks * 4 + quad) ^ swz) * 8));
#pragma unroll
      for (int j = 0; j < 4; ++j)
        bfr[j] = *(const bf16x8*)(sB + (wn + j * 16 + lrow) * 64 +
                                  (((ks * 4 + quad) ^ swz) * 8));
#pragma unroll
      for (int i = 0; i < 4; ++i)
#pragma unroll
        for (int j = 0; j < 4; ++j)
          acc[i][j] = __builtin_amdgcn_mfma_f32_16x16x32_bf16(af[i], bfr[j], acc[i][j], 0, 0, 0);
    }
  }

  float bv[4];
#pragma unroll
  for (int j = 0; j < 4; ++j) bv[j] = bias[n0 + wn + j * 16 + lrow];

  if constexpr (MODE == 2) {
    const int h = (n0 + wn) >> 6;
    const float g = gamma[h];
    bf16_t* qn = (bf16_t*)Cout;
#pragma unroll
    for (int i = 0; i < 4; ++i) {
#pragma unroll
      for (int r = 0; r < 4; ++r) {
        float val[4];
        float ss = 0.f;
#pragma unroll
        for (int j = 0; j < 4; ++j) {
          val[j] = acc[i][j][r] + bv[j];
          ss += val[j] * val[j];
        }
        ss += __shfl_xor(ss, 1);
        ss += __shfl_xor(ss, 2);
        ss += __shfl_xor(ss, 4);
        ss += __shfl_xor(ss, 8);
        float scale = g * rsqrtf(ss);
        int row = m0 + wm + i * 16 + quad * 4 + r;
        int b_ = row >> 12, n = row & (SEQ - 1);
        bf16_t* dst = qn + ((size_t)(b_ * NH + h) * SEQ + n) * 64;
#pragma unroll
        for (int j = 0; j < 4; ++j) dst[j * 16 + lrow] = (bf16_t)(val[j] * scale);
      }
    }
  } else if constexpr (MODE == 1) {
    float* C = (float*)Cout;
#pragma unroll
    for (int i = 0; i < 4; ++i) {
      int row = m0 + wm + i * 16 + quad * 4;
#pragma unroll
      for (int j = 0; j < 4; ++j) {
        int col = n0 + wn + j * 16 + lrow;
#pragma unroll
        for (int r = 0; r < 4; ++r)
          C[(size_t)(row + r) * N + col] = acc[i][j][r] + bv[j];
      }
    }
  } else {
    bf16_t* C = (bf16_t*)Cout;
#pragma unroll
    for (int i = 0; i < 4; ++i) {
      int row = m0 + wm + i * 16 + quad * 4;
#pragma unroll
      for (int j = 0; j < 4; ++j) {
        int col = n0 + wn + j * 16 + lrow;
#pragma unroll
        for (int r = 0; r < 4; ++r)
          C[(size_t)(row + r) * N + col] = (bf16_t)(acc[i][j][r] + bv[j]);
      }
    }
  }
}

// ---------------- kv accumulation via MFMA: kv[bh] += K_chunk^T * V_chunk ----------------
// grid: 64 bh * 8 chunks (512 n-rows each). LDS tiles [128][66] (stride 66: quad's
// +8 rows = +1056B = +8 banks -> transpose scalar reads conflict-free).
#define KVCH 512
__global__ __launch_bounds__(256) void kv_accum_mfma(const bf16_t* __restrict__ kp,
                                                     const bf16_t* __restrict__ vp,
                                                     float* __restrict__ kv) {
  __shared__ bf16_t sK[128][66];
  __shared__ bf16_t sV[128][66];
  int bx = blockIdx.x;
  int chunk = bx & 7;
  int bh = bx >> 3;
  int b = bh >> 4, h = bh & 15;
  int tid = threadIdx.x, lane = tid & 63, wave = tid >> 6;
  int lrow = lane & 15, quad = lane >> 4;

  f32x4 zero = {0.f, 0.f, 0.f, 0.f};
  f32x4 acc[4][4];
#pragma unroll
  for (int i = 0; i < 4; ++i)
#pragma unroll
    for (int j = 0; j < 4; ++j) acc[i][j] = zero;

  const int srow = tid >> 3;        // 0..31
  const int scol = (tid & 7) * 8;
  const size_t gbase0 = ((size_t)(b * SEQ + chunk * KVCH)) * DMODEL + h * 64 + scol;
  const int krow0 = wave * 32 + quad * 8;

  for (int s = 0; s < KVCH / 128; ++s) {
    bf16x8 kr[4], vr[4];
#pragma unroll
    for (int p = 0; p < 4; ++p) {
      size_t g = gbase0 + (size_t)(s * 128 + p * 32 + srow) * DMODEL;
      kr[p] = *(const bf16x8*)(kp + g);
      vr[p] = *(const bf16x8*)(vp + g);
    }
    __syncthreads();
#pragma unroll
    for (int p = 0; p < 4; ++p) {
      *(bf16x8*)&sK[p * 32 + srow][scol] = kr[p];
      *(bf16x8*)&sV[p * 32 + srow][scol] = vr[p];
    }
    __syncthreads();
    bf16x8 af[4], bfr[4];
#pragma unroll
    for (int i = 0; i < 4; ++i)
#pragma unroll
      for (int j = 0; j < 8; ++j) {
        af[i][j]  = sK[krow0 + j][i * 16 + lrow];
        bfr[i][j] = sV[krow0 + j][i * 16 + lrow];
      }
#pragma unroll
    for (int i = 0; i < 4; ++i)
#pragma unroll
      for (int j = 0; j < 4; ++j)
        acc[i][j] = __builtin_amdgcn_mfma_f32_16x16x32_bf16(af[i], bfr[j], acc[i][j], 0, 0, 0);
  }

  float* dst = kv + (size_t)bh * 64 * 64;
#pragma unroll
  for (int i = 0; i < 4; ++i)
#pragma unroll
    for (int j = 0; j < 4; ++j)
#pragma unroll
      for (int r = 0; r < 4; ++r)
        atomicAdd(&dst[(i * 16 + quad * 4 + r) * 64 + j * 16 + lrow], acc[i][j][r]);
}

// ---------------- attention apply with fused kv-norm ----------------
// att[b,n,h*64+vv] = sum_kk qn[bh,n,kk] * (kv[bh,kk,vv]*gamma[h]/||kv[bh,kk,:]||)
// Per block: stage kv[bh] fp32 in LDS [64][65] (stride 65: quad +8 rows = +520w = +8 banks),
// compute row norms, build B-frags by transpose-read + scale + cvt.
__global__ __launch_bounds__(256) void attn_gemm(const bf16_t* __restrict__ qn,
                                                 const float* __restrict__ kv,
                                                 const float* __restrict__ gamma,
                                                 bf16_t* __restrict__ att) {
  __shared__ float sKV[64][65];
  __shared__ float sScale[64];
  int bx = blockIdx.x;          // bh*32 + chunk
  int chunk = bx & 31, bh = bx >> 5;
  int b = bh >> 4, h = bh & 15;
  int tid = threadIdx.x, lane = tid & 63, wave = tid >> 6;
  int lrow = lane & 15, quad = lane >> 4;
  int n0 = chunk * 128 + wave * 32;

  // stage kv (4096 floats): thread t loads row t>>2, 16 cols at (t&3)*16
  {
    const float* src = kv + (size_t)bh * 64 * 64 + (tid >> 2) * 64 + (tid & 3) * 16;
    float4 v0 = *(const float4*)src;
    float4 v1 = *(const float4*)(src + 4);
    float4 v2 = *(const float4*)(src + 8);
    float4 v3 = *(const float4*)(src + 12);
    float* d = &sKV[tid >> 2][(tid & 3) * 16];
    *(float4*)d = v0; *(float4*)(d + 4) = v1; *(float4*)(d + 8) = v2; *(float4*)(d + 12) = v3;
    // row-norm partial from the registers we already hold
    float ss = v0.x*v0.x + v0.y*v0.y + v0.z*v0.z + v0.w*v0.w
             + v1.x*v1.x + v1.y*v1.y + v1.z*v1.z + v1.w*v1.w
             + v2.x*v2.x + v2.y*v2.y + v2.z*v2.z + v2.w*v2.w
             + v3.x*v3.x + v3.y*v3.y + v3.z*v3.z + v3.w*v3.w;
    ss += __shfl_xor(ss, 1);
    ss += __shfl_xor(ss, 2);
    if ((tid & 3) == 0) sScale[tid >> 2] = gamma[h] * rsqrtf(ss);
  }
  __syncthreads();

  const bf16_t* qbase = qn + (size_t)bh * SEQ * 64;
  f32x4 zero = {0.f, 0.f, 0.f, 0.f};
  f32x4 acc[2][4];
#pragma unroll
  for (int i = 0; i < 2; ++i)
#pragma unroll
    for (int j = 0; j < 4; ++j) acc[i][j] = zero;

#pragma unroll
  for (int ks = 0; ks < 2; ++ks) {
    int k0 = ks * 32 + quad * 8;
    bf16x8 af[2], bfr[4];
#pragma unroll
    for (int i = 0; i < 2; ++i)
      af[i] = *(const bf16x8*)(qbase + (size_t)(n0 + i * 16 + lrow) * 64 + k0);
    float sc[8];
#pragma unroll
    for (int j = 0; j < 8; ++j) sc[j] = sScale[k0 + j];
#pragma unroll
    for (int jt = 0; jt < 4; ++jt)
#pragma unroll
      for (int j = 0; j < 8; ++j)
        bfr[jt][j] = (bf16_t)(sKV[k0 + j][jt * 16 + lrow] * sc[j]);
#pragma unroll
    for (int i = 0; i < 2; ++i)
#pragma unroll
      for (int j = 0; j < 4; ++j)
        acc[i][j] = __builtin_amdgcn_mfma_f32_16x16x32_bf16(af[i], bfr[j], acc[i][j], 0, 0, 0);
  }
#pragma unroll
  for (int i = 0; i < 2; ++i)
#pragma unroll
    for (int j = 0; j < 4; ++j)
#pragma unroll
      for (int r = 0; r < 4; ++r) {
        int n = n0 + i * 16 + quad * 4 + r;
        att[((size_t)(b * SEQ + n)) * DMODEL + h * 64 + j * 16 + lrow] = (bf16_t)acc[i][j][r];
      }
}

// ---------------- launch ----------------
extern "C" void kernel_launch(void* const* d_in, const int* in_sizes, int n_in,
                              void* d_out, int out_size, void* d_ws, size_t ws_size,
                              hipStream_t stream) {
  const float* queries = (const float*)d_in[0];
  const float* keys    = (const float*)d_in[1];
  const float* values  = (const float*)d_in[2];
  const float* Wq = (const float*)d_in[3];
  const float* bq = (const float*)d_in[4];
  const float* Wk = (const float*)d_in[5];
  const float* bk = (const float*)d_in[6];
  const float* Wv = (const float*)d_in[7];
  const float* bv = (const float*)d_in[8];
  const float* Wo = (const float*)d_in[9];
  const float* bo = (const float*)d_in[10];
  const float* gamma = (const float*)d_in[11];

  char* ws = (char*)d_ws;
  size_t off = 0;
  auto alloc = [&](size_t bytes) -> void* {
    void* p = ws + off;
    off = (off + bytes + 255) & ~(size_t)255;
    return p;
  };
  const size_t actN = (size_t)NROWS * DMODEL;
  bf16_t* wqb  = (bf16_t*)alloc((size_t)DMODEL * DMODEL * 2);
  bf16_t* wkb  = (bf16_t*)alloc((size_t)DMODEL * DMODEL * 2);
  bf16_t* wvb  = (bf16_t*)alloc((size_t)DMODEL * DMODEL * 2);
  bf16_t* wob  = (bf16_t*)alloc((size_t)DMODEL * DMODEL * 2);
  bf16_t* actb = (bf16_t*)alloc(actN * 2);   // rotating bf16 A-operand buffer
  bf16_t* bufA = (bf16_t*)alloc(actN * 2);   // kproj, later qn
  bf16_t* bufB = (bf16_t*)alloc(actN * 2);   // vproj, later att
  float*  kv   = (float*)alloc((size_t)64 * 64 * 64 * 4);

  int w8 = DMODEL * DMODEL / 8;
  int act8 = (int)(actN / 8);
  const int gemm_grid = (NROWS / 128) * (DMODEL / 128);  // 1024

  // weights + kv zero in one dispatch
  f2b4_kernel<<<dim3(w8 / 256, 5), 256, 0, stream>>>(Wk, wkb, Wv, wvb, Wq, wqb, Wo, wob,
                                                     kv, 64 * 64 * 64 / 4, w8);

  // K projection
  f2b_kernel<<<act8 / 256, 256, 0, stream>>>(keys, actb, act8);
  gemm_bt<0><<<gemm_grid, 256, 0, stream>>>(actb, wkb, bk, bufA, nullptr, NROWS, DMODEL, DMODEL);
  // V projection
  f2b_kernel<<<act8 / 256, 256, 0, stream>>>(values, actb, act8);
  gemm_bt<0><<<gemm_grid, 256, 0, stream>>>(actb, wvb, bv, bufB, nullptr, NROWS, DMODEL, DMODEL);

  // kv accumulation (MFMA)
  kv_accum_mfma<<<64 * 8, 256, 0, stream>>>(bufA, bufB, kv);

  // Q projection with fused xnorm -> qn (into bufA, dead kproj)
  f2b_kernel<<<act8 / 256, 256, 0, stream>>>(queries, actb, act8);
  gemm_bt<2><<<gemm_grid, 256, 0, stream>>>(actb, wqb, bq, bufA, gamma, NROWS, DMODEL, DMODEL);

  // attention apply with fused kv-norm -> att (into bufB, dead vproj)
  attn_gemm<<<64 * 32, 256, 0, stream>>>(bufA, kv, gamma, bufB);

  // output projection (fp32 out + bias)
  gemm_bt<1><<<gemm_grid, 256, 0, stream>>>(bufB, wob, bo, d_out, nullptr, NROWS, DMODEL, DMODEL);
}